// Round 3
// baseline (3049.492 us; speedup 1.0000x reference)
//
#include <hip/hip_runtime.h>
#include <stdint.h>

// Problem constants
#define Bb   128
#define Tt   256
#define Nn   4
#define Dd   64
#define Hh   256
#define G4H  1024          // 4*H
#define MR   64            // episode lanes (rows) per work item

// d_out layout: output (B,T,N,H) | h_n (B,N,L,H) | c_n (B,N,L,H)
#define OUT_HN 33554432    // 128*256*4*256
#define OUT_CN 33816576    // OUT_HN + 128*4*2*256

// workspace byte offsets
#define WS_CTRL 0          // 64 ints: [0]=stride mode, [1]=E, [2]=nchunks, [4..7]=work ctrs
#define WS_HIST 1024       // 257 ints
#define WS_OFFS 3072       // 257 ints
#define WS_SORT 8192       // 32768 u32 packed episodes (sorted desc by len)
#define WS_BIAS 139264     // N*2*1024 f32 packed bias
#define WS_WPK  262144     // packed bf16 weights: 4 agents * 1664 tiles * 1KB
#define TILES_PER_AGENT 1664   // 64 ntiles * (10 kb L0 + 16 kb L1)

typedef __attribute__((ext_vector_type(4))) float f32x4;
typedef __attribute__((ext_vector_type(8))) short bf16x8;

__device__ __forceinline__ unsigned short f2bf(float f){
  union { float f; unsigned u; } v; v.f = f;
  unsigned r = v.u + 0x7FFFu + ((v.u >> 16) & 1u);  // RNE
  return (unsigned short)(r >> 16);
}
__device__ __forceinline__ float bf2f(short s){
  union { unsigned u; float f; } v; v.u = ((unsigned)(unsigned short)s) << 16;
  return v.f;
}
__device__ __forceinline__ float sigm(float x){ return 1.f / (1.f + __expf(-x)); }
__device__ __forceinline__ float tanh_s(float x){ return 1.f - 2.f / (1.f + __expf(2.f * x)); }

// Hardware XCD id (m09-verified on gfx950). All waves of a block share a CU -> uniform.
__device__ __forceinline__ int get_xcc(){
  unsigned v;
  asm volatile("s_getreg_b32 %0, hwreg(HW_REG_XCC_ID)" : "=s"(v));
  return (int)(v & 7);
}

// ---- LDS swizzle helpers (XOR bit4 with row&7 -> conflict-free b128 column reads) ----
__device__ __forceinline__ void st_h(unsigned short* hl, int row, int col, unsigned short v){
  int off = (row * (Hh*2) + col * 2) ^ ((row & 7) << 4);
  *(unsigned short*)((char*)hl + off) = v;
}
__device__ __forceinline__ bf16x8 ld_hfrag(const unsigned short* hl, int m, int kb, int l){
  int row = m*16 + (l & 15);
  int off = (row * (Hh*2) + kb*64 + ((l >> 4) << 4)) ^ ((row & 7) << 4);
  return *(const bf16x8*)((const char*)hl + off);
}
__device__ __forceinline__ bf16x8 ld_xfrag(const unsigned short* xl, int m, int kb, int l){
  int row = m*16 + (l & 15);
  int off = (row * (Dd*2) + kb*64 + ((l >> 4) << 4)) ^ ((row & 7) << 4);
  return *(const bf16x8*)((const char*)xl + off);
}

// ============== prep kernels ==============

// Detect is_init storage: bool8 (stride 1) vs int32/float32 (stride 4).
__global__ void k_detect(const unsigned char* ii, int* ctrl){
  int t = threadIdx.x;
  int cnt = 0;
  for (int i = t; i < 256; i += 64) cnt += (ii[i] != 0);
  for (int o = 32; o; o >>= 1) cnt += __shfl_down(cnt, o, 64);
  if (t == 0) ctrl[0] = (cnt > 80) ? 1 : 4;
}

__device__ __forceinline__ bool get_flag(const unsigned char* p, int t, int stride){
  if (stride == 1) return p[t] != 0;
  return ((const int*)p)[t] != 0;   // covers int32 and f32 bit patterns
}

__global__ void k_extract(const unsigned char* ii, const int* ctrl, int* hist){
  int b = threadIdx.x; if (b >= Bb) return;
  int stride = ctrl[0];
  const unsigned char* p = ii + (size_t)b * Tt * stride;
  int start = 0;
  for (int t = 1; t < Tt; t++){
    if (get_flag(p, t, stride)){ atomicAdd(&hist[t - start], 1); start = t; }
  }
  atomicAdd(&hist[Tt - start], 1);
}

__global__ void k_scan(int* ctrl, const int* hist, int* offs){
  if (threadIdx.x != 0) return;
  int run = 0;
  for (int len = Tt; len >= 1; len--){ offs[len] = run; run += hist[len]; }
  ctrl[1] = run;                       // E = total episodes
  ctrl[2] = (run + MR - 1) / MR;       // nchunks
}

__global__ void k_scatter(const unsigned char* ii, const int* ctrl, int* offs,
                          unsigned int* sorted){
  int b = threadIdx.x; if (b >= Bb) return;
  int stride = ctrl[0];
  const unsigned char* p = ii + (size_t)b * Tt * stride;
  int start = 0;
  for (int t = 1; t < Tt; t++){
    if (get_flag(p, t, stride)){
      int len = t - start;
      int pos = atomicAdd(&offs[len], 1);
      sorted[pos] = 0x80000000u | ((unsigned)b << 16) | ((unsigned)start << 8) | (unsigned)(len - 1);
      start = t;
    }
  }
  int len = Tt - start;
  int pos = atomicAdd(&offs[len], 1);
  sorted[pos] = 0x80000000u | ((unsigned)b << 16) | ((unsigned)start << 8) | (unsigned)(len - 1);
}

// Pack weights to bf16 in exact MFMA B-fragment order.
// Coalesced read mapping: 4 consecutive lanes read one contiguous 128B k-segment.
// lane l: col_sub = l>>2 (0..15), k8 = (l&3)*8. Write lane lp = ((l&3)<<4)|(l>>2)
// so dst fragment (lp&15)=col_sub, (lp>>4)*8=k8 -- identical tile layout as before.
__global__ void k_packw(const float* __restrict__ Wih0, const float* __restrict__ Whh0,
                        const float* __restrict__ Wih1, const float* __restrict__ Whh1,
                        unsigned short* __restrict__ wpk){
  int bid = blockIdx.x;            // 0..6655
  int l = threadIdx.x;             // 0..63
  int n = bid / TILES_PER_AGENT;
  int r = bid % TILES_PER_AGENT;
  int layer, ntile, kb;
  if (r < 640){ layer = 0; ntile = r / 10; kb = r % 10; }
  else        { layer = 1; r -= 640; ntile = r / 16; kb = r % 16; }
  int col_sub = l >> 2;
  int k8      = (l & 3) * 8;
  int col  = ntile*16 + col_sub;
  int grow = (col & 3)*Hh + (col >> 2);
  const float* src;
  if (layer == 0){
    if (kb < 2) src = Wih0 + ((size_t)(n*G4H + grow))*Dd + kb*32 + k8;        // x part
    else        src = Whh0 + ((size_t)(n*G4H + grow))*Hh + (kb-2)*32 + k8;    // h0 part
  } else {
    if (kb < 8) src = Wih1 + ((size_t)(n*G4H + grow))*Hh + kb*32 + k8;        // h0_new part
    else        src = Whh1 + ((size_t)(n*G4H + grow))*Hh + (kb-8)*32 + k8;    // h1 part
  }
  int tl = (layer == 0) ? (ntile*10 + kb) : (640 + ntile*16 + kb);
  int lp = ((l & 3) << 4) | (l >> 2);
  unsigned short* dst = wpk + (((size_t)n*TILES_PER_AGENT + tl)*64 + lp)*8;
  #pragma unroll
  for (int j = 0; j < 8; j++) dst[j] = f2bf(src[j]);
}

__global__ void k_packb(const float* __restrict__ bih0, const float* __restrict__ bhh0,
                        const float* __restrict__ bih1, const float* __restrict__ bhh1,
                        float* __restrict__ bpk){
  int id = blockIdx.x*blockDim.x + threadIdx.x;
  if (id >= Nn*2*G4H) return;
  int n = id >> 11; int r = id & 2047; int layer = r >> 10; int c = r & 1023;
  int grow = (c & 3)*Hh + (c >> 2);
  float v = (layer == 0) ? (bih0[n*G4H + grow] + bhh0[n*G4H + grow])
                         : (bih1[n*G4H + grow] + bhh1[n*G4H + grow]);
  bpk[id] = v;
}

// ============== main kernel ==============
// 256 blocks x 512 threads. Agent = HW XCD id & 3 -> each XCD L2 holds exactly
// one agent's packed weights (1.66 MB < 4 MB), independent of dispatch policy.
// Work item = chunk of 64 sorted episodes (MR=64): each 1.66MB weight stream is
// amortized over 4 M-tiles (2x fewer steps, 2x less weight traffic than MR=32).
__launch_bounds__(512, 2)
__global__ void k_main(const float* __restrict__ x_in,
                       const unsigned short* __restrict__ wpk,
                       const float* __restrict__ bpk,
                       const unsigned int* __restrict__ sorted,
                       int* __restrict__ ctrl,
                       float* __restrict__ out)
{
  __shared__ unsigned short h0l[MR*Hh];     // 32KB, swizzled bf16
  __shared__ unsigned short h1l[MR*Hh];     // 32KB
  __shared__ unsigned short xl [MR*Dd];     // 8KB
  __shared__ float biasl[2*G4H];            // 8KB
  __shared__ float gbuf[8][16*20];          // per-wave gate transpose staging, 10KB
  __shared__ unsigned int epl[MR];
  __shared__ int item_s;

  const int tid = threadIdx.x;
  const int w   = tid >> 6;
  const int l   = tid & 63;
  const int n   = get_xcc() & 3;            // agent pinned to this XCD
  const int E       = ctrl[1];
  const int nchunks = ctrl[2];

  for (int i = tid; i < 2*G4H; i += 512) biasl[i] = bpk[n*2*G4H + i];
  const unsigned short* wbase = wpk + (size_t)n * TILES_PER_AGENT * 64 * 8;

  const int nrow = l & 15;   // nonlin: row within M-tile
  const int nul  = l >> 4;   // nonlin: unit_local 0..3

  while (true){
    __syncthreads();
    if (tid == 0) item_s = atomicAdd(&ctrl[4 + n], 1);
    __syncthreads();
    int chunk = item_s;
    if (chunk >= nchunks) break;

    if (tid < MR){
      int idx = chunk*MR + tid;
      epl[tid] = (idx < E) ? sorted[idx] : 0u;
    }
    for (int i = tid; i < MR*Hh/4; i += 512){
      ((ushort4*)h0l)[i] = make_ushort4(0,0,0,0);
      ((ushort4*)h1l)[i] = make_ushort4(0,0,0,0);
    }
    __syncthreads();

    unsigned int ep0 = epl[0];
    int maxlen = (ep0 >> 31) ? (int)(ep0 & 255) + 1 : 0;  // sorted desc -> lane0 is max

    float c0r[8][4], c1r[8][4];
    #pragma unroll
    for (int i = 0; i < 8; i++)
      #pragma unroll
      for (int m = 0; m < 4; m++){ c0r[i][m]=0.f; c1r[i][m]=0.f; }

    #pragma unroll 1
    for (int s = 0; s < maxlen; s++){
      // ---- stage x_t (fp32 -> bf16, swizzled; zeros for finished lanes) ----
      #pragma unroll
      for (int r2 = 0; r2 < 2; r2++){
        int row = r2*32 + (tid >> 4);
        int d4  = (tid & 15) * 4;
        unsigned int pk = epl[row];
        int len = (pk >> 31) ? (int)(pk & 255) + 1 : 0;
        ushort4 u = make_ushort4(0,0,0,0);
        if (s < len){
          int b = (pk >> 16) & 127;
          int t = (int)((pk >> 8) & 255) + s;
          const float* xp = x_in + (((size_t)b*Tt + t)*Nn + n)*Dd + d4;
          f32x4 v = __builtin_nontemporal_load((const f32x4*)xp);
          u.x = f2bf(v[0]); u.y = f2bf(v[1]); u.z = f2bf(v[2]); u.w = f2bf(v[3]);
        }
        int off = (row*(Dd*2) + d4*2) ^ ((row & 7) << 4);
        *(ushort4*)((char*)xl + off) = u;
      }
      __syncthreads();

      // ================= LAYER 0 =================
      {
        f32x4 acc[8][4];
        #pragma unroll
        for (int i = 0; i < 8; i++){
          float bv = biasl[(w*8 + i)*16 + (l & 15)];
          f32x4 z = {bv, bv, bv, bv};
          #pragma unroll
          for (int m = 0; m < 4; m++) acc[i][m] = z;
        }
        for (int kb = 0; kb < 10; kb++){
          bf16x8 a0, a1, a2, a3;
          if (kb < 2){
            a0 = ld_xfrag(xl, 0, kb, l); a1 = ld_xfrag(xl, 1, kb, l);
            a2 = ld_xfrag(xl, 2, kb, l); a3 = ld_xfrag(xl, 3, kb, l);
          } else {
            a0 = ld_hfrag(h0l, 0, kb-2, l); a1 = ld_hfrag(h0l, 1, kb-2, l);
            a2 = ld_hfrag(h0l, 2, kb-2, l); a3 = ld_hfrag(h0l, 3, kb-2, l);
          }
          #pragma unroll
          for (int i = 0; i < 8; i++){
            const bf16x8 bf = *(const bf16x8*)(wbase + (((size_t)((w*8+i)*10 + kb))*64 + l)*8);
            acc[i][0] = __builtin_amdgcn_mfma_f32_16x16x32_bf16(a0, bf, acc[i][0], 0, 0, 0);
            acc[i][1] = __builtin_amdgcn_mfma_f32_16x16x32_bf16(a1, bf, acc[i][1], 0, 0, 0);
            acc[i][2] = __builtin_amdgcn_mfma_f32_16x16x32_bf16(a2, bf, acc[i][2], 0, 0, 0);
            acc[i][3] = __builtin_amdgcn_mfma_f32_16x16x32_bf16(a3, bf, acc[i][3], 0, 0, 0);
          }
        }
        __syncthreads();   // all h0/x reads done before h0 is overwritten

        // nonlinearity (per-wave LDS transpose; no cross-wave sync needed)
        #pragma unroll
        for (int i = 0; i < 8; i++){
          #pragma unroll
          for (int m = 0; m < 4; m++){
            *(f32x4*)&gbuf[w][(l & 15)*20 + ((l >> 4) << 2)] = acc[i][m];
            asm volatile("" ::: "memory");
            float gi = gbuf[w][(nul*4 + 0)*20 + nrow];
            float gf = gbuf[w][(nul*4 + 1)*20 + nrow];
            float gg = gbuf[w][(nul*4 + 2)*20 + nrow];
            float go = gbuf[w][(nul*4 + 3)*20 + nrow];
            asm volatile("" ::: "memory");
            float cn = sigm(gf)*c0r[i][m] + sigm(gi)*tanh_s(gg);
            float hn = sigm(go)*tanh_s(cn);
            c0r[i][m] = cn;
            int row  = m*16 + nrow;
            int unit = (w*8 + i)*4 + nul;
            st_h(h0l, row, unit, f2bf(hn));
            unsigned int pk = epl[row];
            if (pk >> 31){
              int len = (int)(pk & 255) + 1;
              int start = (pk >> 8) & 255;
              if (s == len - 1 && start + len == Tt){
                int b = (pk >> 16) & 127;
                size_t base = ((size_t)(b*Nn + n)*2 + 0)*Hh + unit;
                __builtin_nontemporal_store(hn, &out[OUT_HN + base]);
                __builtin_nontemporal_store(cn, &out[OUT_CN + base]);
              }
            }
          }
        }
      }
      __syncthreads();   // h0_new visible to all waves

      // ================= LAYER 1 =================
      {
        f32x4 acc[8][4];
        #pragma unroll
        for (int i = 0; i < 8; i++){
          float bv = biasl[G4H + (w*8 + i)*16 + (l & 15)];
          f32x4 z = {bv, bv, bv, bv};
          #pragma unroll
          for (int m = 0; m < 4; m++) acc[i][m] = z;
        }
        for (int kb = 0; kb < 16; kb++){
          bf16x8 a0, a1, a2, a3;
          if (kb < 8){
            a0 = ld_hfrag(h0l, 0, kb, l); a1 = ld_hfrag(h0l, 1, kb, l);
            a2 = ld_hfrag(h0l, 2, kb, l); a3 = ld_hfrag(h0l, 3, kb, l);
          } else {
            a0 = ld_hfrag(h1l, 0, kb-8, l); a1 = ld_hfrag(h1l, 1, kb-8, l);
            a2 = ld_hfrag(h1l, 2, kb-8, l); a3 = ld_hfrag(h1l, 3, kb-8, l);
          }
          #pragma unroll
          for (int i = 0; i < 8; i++){
            const bf16x8 bf = *(const bf16x8*)(wbase + (((size_t)(640 + (w*8+i)*16 + kb))*64 + l)*8);
            acc[i][0] = __builtin_amdgcn_mfma_f32_16x16x32_bf16(a0, bf, acc[i][0], 0, 0, 0);
            acc[i][1] = __builtin_amdgcn_mfma_f32_16x16x32_bf16(a1, bf, acc[i][1], 0, 0, 0);
            acc[i][2] = __builtin_amdgcn_mfma_f32_16x16x32_bf16(a2, bf, acc[i][2], 0, 0, 0);
            acc[i][3] = __builtin_amdgcn_mfma_f32_16x16x32_bf16(a3, bf, acc[i][3], 0, 0, 0);
          }
        }
        __syncthreads();   // h1 reads done before h1 is overwritten

        #pragma unroll
        for (int i = 0; i < 8; i++){
          #pragma unroll
          for (int m = 0; m < 4; m++){
            *(f32x4*)&gbuf[w][(l & 15)*20 + ((l >> 4) << 2)] = acc[i][m];
            asm volatile("" ::: "memory");
            float gi = gbuf[w][(nul*4 + 0)*20 + nrow];
            float gf = gbuf[w][(nul*4 + 1)*20 + nrow];
            float gg = gbuf[w][(nul*4 + 2)*20 + nrow];
            float go = gbuf[w][(nul*4 + 3)*20 + nrow];
            asm volatile("" ::: "memory");
            float cn = sigm(gf)*c1r[i][m] + sigm(gi)*tanh_s(gg);
            float hn = sigm(go)*tanh_s(cn);
            c1r[i][m] = cn;
            int row  = m*16 + nrow;
            int unit = (w*8 + i)*4 + nul;
            st_h(h1l, row, unit, f2bf(hn));
            unsigned int pk = epl[row];
            if (pk >> 31){
              int len = (int)(pk & 255) + 1;
              int start = (pk >> 8) & 255;
              if (s == len - 1 && start + len == Tt){
                int b = (pk >> 16) & 127;
                size_t base = ((size_t)(b*Nn + n)*2 + 1)*Hh + unit;
                __builtin_nontemporal_store(hn, &out[OUT_HN + base]);
                __builtin_nontemporal_store(cn, &out[OUT_CN + base]);
              }
            }
          }
        }
      }
      __syncthreads();   // h1_new visible

      // ---- output write: output[b, t, n, :] = h1_new ----
      // Full-line coalesced: each instruction writes one contiguous 256B
      // segment (16 lanes x f32x4), 4 per row.
      #pragma unroll
      for (int r2 = 0; r2 < 2; r2++){
        int row = r2*32 + (tid >> 4);
        unsigned int pk = epl[row];
        int len = (pk >> 31) ? (int)(pk & 255) + 1 : 0;
        if (s < len){
          int b = (pk >> 16) & 127;
          int t = (int)((pk >> 8) & 255) + s;
          int l16 = tid & 15;
          int swz = (row & 7) << 4;
          float* op = out + (((size_t)b*Tt + t)*Nn + n)*Hh;
          #pragma unroll
          for (int k = 0; k < 4; k++){
            int off = (row*(Hh*2) + k*128 + l16*8) ^ swz;
            ushort4 u = *(const ushort4*)((const char*)h1l + off);
            f32x4 v = { bf2f((short)u.x), bf2f((short)u.y), bf2f((short)u.z), bf2f((short)u.w) };
            __builtin_nontemporal_store(v, (f32x4*)(op + k*64 + l16*4));
          }
        }
      }
    } // s loop
  } // work loop
}

// ============== launch ==============
extern "C" void kernel_launch(void* const* d_in, const int* in_sizes, int n_in,
                              void* d_out, int out_size, void* d_ws, size_t ws_size,
                              hipStream_t stream)
{
  const float* x    = (const float*)d_in[0];
  const unsigned char* ii = (const unsigned char*)d_in[1];
  const float* Wih0 = (const float*)d_in[2];
  const float* Whh0 = (const float*)d_in[3];
  const float* bih0 = (const float*)d_in[4];
  const float* bhh0 = (const float*)d_in[5];
  const float* Wih1 = (const float*)d_in[6];
  const float* Whh1 = (const float*)d_in[7];
  const float* bih1 = (const float*)d_in[8];
  const float* bhh1 = (const float*)d_in[9];
  float* out = (float*)d_out;
  char* ws = (char*)d_ws;

  int* ctrl = (int*)(ws + WS_CTRL);
  int* hist = (int*)(ws + WS_HIST);
  int* offs = (int*)(ws + WS_OFFS);
  unsigned int* sorted = (unsigned int*)(ws + WS_SORT);
  float* bpk = (float*)(ws + WS_BIAS);
  unsigned short* wpkp = (unsigned short*)(ws + WS_WPK);

  hipMemsetAsync(d_ws, 0, 8192, stream);
  k_detect <<<1, 64, 0, stream>>>(ii, ctrl);
  k_extract<<<1, 128, 0, stream>>>(ii, ctrl, hist);
  k_scan   <<<1, 1, 0, stream>>>(ctrl, hist, offs);
  k_scatter<<<1, 128, 0, stream>>>(ii, ctrl, offs, sorted);
  k_packw  <<<Nn*TILES_PER_AGENT, 64, 0, stream>>>(Wih0, Whh0, Wih1, Whh1, wpkp);
  k_packb  <<<32, 256, 0, stream>>>(bih0, bhh0, bih1, bhh1, bpk);
  k_main   <<<256, 512, 0, stream>>>(x, wpkp, bpk, sorted, ctrl, out);
}

// Round 5
// 1374.203 us; speedup vs baseline: 2.2191x; 2.2191x over previous
//
#include <hip/hip_runtime.h>
#include <stdint.h>

// Problem constants
#define Bb   128
#define Tt   256
#define Nn   4
#define Dd   64
#define Hh   256
#define G4H  1024          // 4*H
#define MR   64            // episode lanes (rows) per work item

// d_out layout: output (B,T,N,H) | h_n (B,N,L,H) | c_n (B,N,L,H)
#define OUT_HN 33554432    // 128*256*4*256
#define OUT_CN 33816576    // OUT_HN + 128*4*2*256

// workspace byte offsets
#define WS_CTRL 0          // 64 ints: [0]=stride mode, [1]=E, [2]=nchunks, [4..7]=work ctrs
#define WS_HIST 1024       // 257 ints
#define WS_OFFS 3072       // 257 ints
#define WS_SORT 8192       // 32768 u32 packed episodes (sorted desc by len)
#define WS_BIAS 139264     // N*2*1024 f32 packed bias
#define WS_WPK  262144     // packed bf16 weights: 4 agents * 1664 tiles * 1KB
#define TILES_PER_AGENT 1664   // 64 ntiles * (10 kb L0 + 16 kb L1)

typedef __attribute__((ext_vector_type(4))) float f32x4;
typedef __attribute__((ext_vector_type(8))) short bf16x8;

__device__ __forceinline__ unsigned short f2bf(float f){
  union { float f; unsigned u; } v; v.f = f;
  unsigned r = v.u + 0x7FFFu + ((v.u >> 16) & 1u);  // RNE
  return (unsigned short)(r >> 16);
}
__device__ __forceinline__ float bf2f(short s){
  union { unsigned u; float f; } v; v.u = ((unsigned)(unsigned short)s) << 16;
  return v.f;
}
// fast sigmoid / tanh via v_exp + v_rcp (absmax margin: 0.004 vs 0.0231 threshold)
__device__ __forceinline__ float sigm(float x){
  return __builtin_amdgcn_rcpf(1.f + __expf(-x));
}
__device__ __forceinline__ float tanh_s(float x){
  return 1.f - 2.f * __builtin_amdgcn_rcpf(1.f + __expf(2.f * x));
}

// ---- LDS swizzle helpers (XOR bit4 with row&7 -> conflict-free b128 column reads) ----
__device__ __forceinline__ void st_h(unsigned short* hl, int row, int col, unsigned short v){
  int off = (row * (Hh*2) + col * 2) ^ ((row & 7) << 4);
  *(unsigned short*)((char*)hl + off) = v;
}
__device__ __forceinline__ bf16x8 ld_hfrag(const unsigned short* hl, int m, int kb, int l){
  int row = m*16 + (l & 15);
  int off = (row * (Hh*2) + kb*64 + ((l >> 4) << 4)) ^ ((row & 7) << 4);
  return *(const bf16x8*)((const char*)hl + off);
}
__device__ __forceinline__ bf16x8 ld_xfrag(const unsigned short* xl, int m, int kb, int l){
  int row = m*16 + (l & 15);
  int off = (row * (Dd*2) + kb*64 + ((l >> 4) << 4)) ^ ((row & 7) << 4);
  return *(const bf16x8*)((const char*)xl + off);
}

// ============== prep kernels ==============

// Detect is_init storage: bool8 (stride 1) vs int32/float32 (stride 4).
__global__ void k_detect(const unsigned char* ii, int* ctrl){
  int t = threadIdx.x;
  int cnt = 0;
  for (int i = t; i < 256; i += 64) cnt += (ii[i] != 0);
  for (int o = 32; o; o >>= 1) cnt += __shfl_down(cnt, o, 64);
  if (t == 0) ctrl[0] = (cnt > 80) ? 1 : 4;
}

__device__ __forceinline__ bool get_flag(const unsigned char* p, int t, int stride){
  if (stride == 1) return p[t] != 0;
  return ((const int*)p)[t] != 0;   // covers int32 and f32 bit patterns
}

__global__ void k_extract(const unsigned char* ii, const int* ctrl, int* hist){
  int b = threadIdx.x; if (b >= Bb) return;
  int stride = ctrl[0];
  const unsigned char* p = ii + (size_t)b * Tt * stride;
  int start = 0;
  for (int t = 1; t < Tt; t++){
    if (get_flag(p, t, stride)){ atomicAdd(&hist[t - start], 1); start = t; }
  }
  atomicAdd(&hist[Tt - start], 1);
}

__global__ void k_scan(int* ctrl, const int* hist, int* offs){
  if (threadIdx.x != 0) return;
  int run = 0;
  for (int len = Tt; len >= 1; len--){ offs[len] = run; run += hist[len]; }
  ctrl[1] = run;                       // E = total episodes
  ctrl[2] = (run + MR - 1) / MR;       // nchunks
}

__global__ void k_scatter(const unsigned char* ii, const int* ctrl, int* offs,
                          unsigned int* sorted){
  int b = threadIdx.x; if (b >= Bb) return;
  int stride = ctrl[0];
  const unsigned char* p = ii + (size_t)b * Tt * stride;
  int start = 0;
  for (int t = 1; t < Tt; t++){
    if (get_flag(p, t, stride)){
      int len = t - start;
      int pos = atomicAdd(&offs[len], 1);
      sorted[pos] = 0x80000000u | ((unsigned)b << 16) | ((unsigned)start << 8) | (unsigned)(len - 1);
      start = t;
    }
  }
  int len = Tt - start;
  int pos = atomicAdd(&offs[len], 1);
  sorted[pos] = 0x80000000u | ((unsigned)b << 16) | ((unsigned)start << 8) | (unsigned)(len - 1);
}

// Pack weights to bf16 in exact MFMA B-fragment order.
// Coalesced read mapping: 4 consecutive lanes read one contiguous 128B k-segment.
__global__ void k_packw(const float* __restrict__ Wih0, const float* __restrict__ Whh0,
                        const float* __restrict__ Wih1, const float* __restrict__ Whh1,
                        unsigned short* __restrict__ wpk){
  int bid = blockIdx.x;            // 0..6655
  int l = threadIdx.x;             // 0..63
  int n = bid / TILES_PER_AGENT;
  int r = bid % TILES_PER_AGENT;
  int layer, ntile, kb;
  if (r < 640){ layer = 0; ntile = r / 10; kb = r % 10; }
  else        { layer = 1; r -= 640; ntile = r / 16; kb = r % 16; }
  int col_sub = l >> 2;
  int k8      = (l & 3) * 8;
  int col  = ntile*16 + col_sub;
  int grow = (col & 3)*Hh + (col >> 2);
  const float* src;
  if (layer == 0){
    if (kb < 2) src = Wih0 + ((size_t)(n*G4H + grow))*Dd + kb*32 + k8;        // x part
    else        src = Whh0 + ((size_t)(n*G4H + grow))*Hh + (kb-2)*32 + k8;    // h0 part
  } else {
    if (kb < 8) src = Wih1 + ((size_t)(n*G4H + grow))*Hh + kb*32 + k8;        // h0_new part
    else        src = Whh1 + ((size_t)(n*G4H + grow))*Hh + (kb-8)*32 + k8;    // h1 part
  }
  int tl = (layer == 0) ? (ntile*10 + kb) : (640 + ntile*16 + kb);
  int lp = ((l & 3) << 4) | (l >> 2);
  unsigned short* dst = wpk + (((size_t)n*TILES_PER_AGENT + tl)*64 + lp)*8;
  #pragma unroll
  for (int j = 0; j < 8; j++) dst[j] = f2bf(src[j]);
}

__global__ void k_packb(const float* __restrict__ bih0, const float* __restrict__ bhh0,
                        const float* __restrict__ bih1, const float* __restrict__ bhh1,
                        float* __restrict__ bpk){
  int id = blockIdx.x*blockDim.x + threadIdx.x;
  if (id >= Nn*2*G4H) return;
  int n = id >> 11; int r = id & 2047; int layer = r >> 10; int c = r & 1023;
  int grow = (c & 3)*Hh + (c >> 2);
  float v = (layer == 0) ? (bih0[n*G4H + grow] + bhh0[n*G4H + grow])
                         : (bih1[n*G4H + grow] + bhh1[n*G4H + grow]);
  bpk[id] = v;
}

// ============== main kernel ==============
// 256 blocks x 512 threads, 1 block/CU (LDS-bound).
// DETERMINISM FIX (R4 diverged post-timing): agent = blockIdx&3, NOT the HW
// XCD id. With XCD-derived agents, replay-time block placement could starve an
// agent's queue for a whole replay (blocks on drained-queue XCDs exit instantly
// and free those CUs for the next blocks -> feedback loop), leaving stale
// output. blockIdx&3 gives exactly 64 blocks per agent on every replay.
// Spill fix from R4 kept: m-split GEMM+nonlin -> live acc [8][2] f32x4.
__launch_bounds__(512, 1)
__global__ void k_main(const float* __restrict__ x_in,
                       const unsigned short* __restrict__ wpk,
                       const float* __restrict__ bpk,
                       const unsigned int* __restrict__ sorted,
                       int* __restrict__ ctrl,
                       float* __restrict__ out)
{
  __shared__ unsigned short h0l[MR*Hh];     // 32KB, swizzled bf16
  __shared__ unsigned short h1l[MR*Hh];     // 32KB
  __shared__ unsigned short xl [MR*Dd];     // 8KB
  __shared__ float biasl[2*G4H];            // 8KB
  __shared__ float gbuf[8][16*20];          // per-wave gate transpose staging, 10KB
  __shared__ unsigned int epl[MR];
  __shared__ int item_s;

  const int tid = threadIdx.x;
  const int w   = tid >> 6;
  const int l   = tid & 63;
  const int n   = blockIdx.x & 3;           // deterministic agent assignment
  const int E       = ctrl[1];
  const int nchunks = ctrl[2];

  for (int i = tid; i < 2*G4H; i += 512) biasl[i] = bpk[n*2*G4H + i];
  const unsigned short* wbase = wpk + (size_t)n * TILES_PER_AGENT * 64 * 8;

  const int nrow = l & 15;   // nonlin: row within M-tile
  const int nul  = l >> 4;   // nonlin: unit_local 0..3

  while (true){
    __syncthreads();
    if (tid == 0) item_s = atomicAdd(&ctrl[4 + n], 1);
    __syncthreads();
    int chunk = item_s;
    if (chunk >= nchunks) break;

    if (tid < MR){
      int idx = chunk*MR + tid;
      epl[tid] = (idx < E) ? sorted[idx] : 0u;
    }
    for (int i = tid; i < MR*Hh/4; i += 512){
      ((ushort4*)h0l)[i] = make_ushort4(0,0,0,0);
      ((ushort4*)h1l)[i] = make_ushort4(0,0,0,0);
    }
    __syncthreads();

    unsigned int ep0 = epl[0];
    int maxlen = (ep0 >> 31) ? (int)(ep0 & 255) + 1 : 0;  // sorted desc -> lane0 is max

    float c0r[8][4], c1r[8][4];
    #pragma unroll
    for (int i = 0; i < 8; i++)
      #pragma unroll
      for (int m = 0; m < 4; m++){ c0r[i][m]=0.f; c1r[i][m]=0.f; }

    #pragma unroll 1
    for (int s = 0; s < maxlen; s++){
      // ---- stage x_t (fp32 -> bf16, swizzled; zeros for finished lanes) ----
      #pragma unroll
      for (int r2 = 0; r2 < 2; r2++){
        int row = r2*32 + (tid >> 4);
        int d4  = (tid & 15) * 4;
        unsigned int pk = epl[row];
        int len = (pk >> 31) ? (int)(pk & 255) + 1 : 0;
        ushort4 u = make_ushort4(0,0,0,0);
        if (s < len){
          int b = (pk >> 16) & 127;
          int t = (int)((pk >> 8) & 255) + s;
          const float* xp = x_in + (((size_t)b*Tt + t)*Nn + n)*Dd + d4;
          f32x4 v = *(const f32x4*)xp;
          u.x = f2bf(v[0]); u.y = f2bf(v[1]); u.z = f2bf(v[2]); u.w = f2bf(v[3]);
        }
        int off = (row*(Dd*2) + d4*2) ^ ((row & 7) << 4);
        *(ushort4*)((char*)xl + off) = u;
      }
      __syncthreads();                                   // bar 1: xl ready

      // ================= LAYER 0 (m-split) =================
      #pragma unroll
      for (int mh = 0; mh < 2; mh++){
        f32x4 acc[8][2];
        #pragma unroll
        for (int i = 0; i < 8; i++){
          float bv = biasl[(w*8 + i)*16 + (l & 15)];
          f32x4 z = {bv, bv, bv, bv};
          acc[i][0] = z; acc[i][1] = z;
        }
        #pragma unroll 2
        for (int kb = 0; kb < 10; kb++){
          bf16x8 a0, a1;
          if (kb < 2){
            a0 = ld_xfrag(xl, mh*2+0, kb, l); a1 = ld_xfrag(xl, mh*2+1, kb, l);
          } else {
            a0 = ld_hfrag(h0l, mh*2+0, kb-2, l); a1 = ld_hfrag(h0l, mh*2+1, kb-2, l);
          }
          #pragma unroll
          for (int i = 0; i < 8; i++){
            const bf16x8 bf = *(const bf16x8*)(wbase + (((size_t)((w*8+i)*10 + kb))*64 + l)*8);
            acc[i][0] = __builtin_amdgcn_mfma_f32_16x16x32_bf16(a0, bf, acc[i][0], 0, 0, 0);
            acc[i][1] = __builtin_amdgcn_mfma_f32_16x16x32_bf16(a1, bf, acc[i][1], 0, 0, 0);
          }
        }
        __syncthreads();   // all waves done reading rows [32mh,32mh+32) (old h0 / x)

        // nonlinearity for rows [32mh, 32mh+32): writes h0 rows disjoint from
        // mh=1's gemm reads (rows 32..63 old) -> no extra barrier needed after.
        #pragma unroll
        for (int i = 0; i < 8; i++){
          #pragma unroll
          for (int ml = 0; ml < 2; ml++){
            int m = mh*2 + ml;
            *(f32x4*)&gbuf[w][(l & 15)*20 + ((l >> 4) << 2)] = acc[i][ml];
            asm volatile("" ::: "memory");
            float gi = gbuf[w][(nul*4 + 0)*20 + nrow];
            float gf = gbuf[w][(nul*4 + 1)*20 + nrow];
            float gg = gbuf[w][(nul*4 + 2)*20 + nrow];
            float go = gbuf[w][(nul*4 + 3)*20 + nrow];
            asm volatile("" ::: "memory");
            float cn = sigm(gf)*c0r[i][m] + sigm(gi)*tanh_s(gg);
            float hn = sigm(go)*tanh_s(cn);
            c0r[i][m] = cn;
            int row  = m*16 + nrow;
            int unit = (w*8 + i)*4 + nul;
            st_h(h0l, row, unit, f2bf(hn));
            unsigned int pk = epl[row];
            if (pk >> 31){
              int len = (int)(pk & 255) + 1;
              int start = (pk >> 8) & 255;
              if (s == len - 1 && start + len == Tt){
                int b = (pk >> 16) & 127;
                size_t base = ((size_t)(b*Nn + n)*2 + 0)*Hh + unit;
                __builtin_nontemporal_store(hn, &out[OUT_HN + base]);
                __builtin_nontemporal_store(cn, &out[OUT_CN + base]);
              }
            }
          }
        }
      }
      __syncthreads();   // all h0_new rows visible for layer 1

      // ================= LAYER 1 (m-split) =================
      #pragma unroll
      for (int mh = 0; mh < 2; mh++){
        f32x4 acc[8][2];
        #pragma unroll
        for (int i = 0; i < 8; i++){
          float bv = biasl[G4H + (w*8 + i)*16 + (l & 15)];
          f32x4 z = {bv, bv, bv, bv};
          acc[i][0] = z; acc[i][1] = z;
        }
        #pragma unroll 2
        for (int kb = 0; kb < 16; kb++){
          bf16x8 a0, a1;
          if (kb < 8){
            a0 = ld_hfrag(h0l, mh*2+0, kb, l); a1 = ld_hfrag(h0l, mh*2+1, kb, l);
          } else {
            a0 = ld_hfrag(h1l, mh*2+0, kb-8, l); a1 = ld_hfrag(h1l, mh*2+1, kb-8, l);
          }
          #pragma unroll
          for (int i = 0; i < 8; i++){
            const bf16x8 bf = *(const bf16x8*)(wbase + (((size_t)(640 + (w*8+i)*16 + kb))*64 + l)*8);
            acc[i][0] = __builtin_amdgcn_mfma_f32_16x16x32_bf16(a0, bf, acc[i][0], 0, 0, 0);
            acc[i][1] = __builtin_amdgcn_mfma_f32_16x16x32_bf16(a1, bf, acc[i][1], 0, 0, 0);
          }
        }
        __syncthreads();   // all waves done reading rows [32mh,..) of h0new/h1old

        #pragma unroll
        for (int i = 0; i < 8; i++){
          #pragma unroll
          for (int ml = 0; ml < 2; ml++){
            int m = mh*2 + ml;
            *(f32x4*)&gbuf[w][(l & 15)*20 + ((l >> 4) << 2)] = acc[i][ml];
            asm volatile("" ::: "memory");
            float gi = gbuf[w][(nul*4 + 0)*20 + nrow];
            float gf = gbuf[w][(nul*4 + 1)*20 + nrow];
            float gg = gbuf[w][(nul*4 + 2)*20 + nrow];
            float go = gbuf[w][(nul*4 + 3)*20 + nrow];
            asm volatile("" ::: "memory");
            float cn = sigm(gf)*c1r[i][m] + sigm(gi)*tanh_s(gg);
            float hn = sigm(go)*tanh_s(cn);
            c1r[i][m] = cn;
            int row  = m*16 + nrow;
            int unit = (w*8 + i)*4 + nul;
            st_h(h1l, row, unit, f2bf(hn));
            unsigned int pk = epl[row];
            if (pk >> 31){
              int len = (int)(pk & 255) + 1;
              int start = (pk >> 8) & 255;
              if (s == len - 1 && start + len == Tt){
                int b = (pk >> 16) & 127;
                size_t base = ((size_t)(b*Nn + n)*2 + 1)*Hh + unit;
                __builtin_nontemporal_store(hn, &out[OUT_HN + base]);
                __builtin_nontemporal_store(cn, &out[OUT_CN + base]);
              }
            }
          }
        }
      }
      __syncthreads();   // h1_new visible for output read

      // ---- output write: output[b, t, n, :] = h1_new (256B segments, NT) ----
      #pragma unroll
      for (int r2 = 0; r2 < 2; r2++){
        int row = r2*32 + (tid >> 4);
        unsigned int pk = epl[row];
        int len = (pk >> 31) ? (int)(pk & 255) + 1 : 0;
        if (s < len){
          int b = (pk >> 16) & 127;
          int t = (int)((pk >> 8) & 255) + s;
          int l16 = tid & 15;
          int swz = (row & 7) << 4;
          float* op = out + (((size_t)b*Tt + t)*Nn + n)*Hh;
          #pragma unroll
          for (int k = 0; k < 4; k++){
            int off = (row*(Hh*2) + k*128 + l16*8) ^ swz;
            ushort4 u = *(const ushort4*)((const char*)h1l + off);
            f32x4 v = { bf2f((short)u.x), bf2f((short)u.y), bf2f((short)u.z), bf2f((short)u.w) };
            __builtin_nontemporal_store(v, (f32x4*)(op + k*64 + l16*4));
          }
        }
      }
      // no trailing barrier needed: next writers of h1l are >=2 barriers away
    } // s loop
  } // work loop
}

// ============== launch ==============
extern "C" void kernel_launch(void* const* d_in, const int* in_sizes, int n_in,
                              void* d_out, int out_size, void* d_ws, size_t ws_size,
                              hipStream_t stream)
{
  const float* x    = (const float*)d_in[0];
  const unsigned char* ii = (const unsigned char*)d_in[1];
  const float* Wih0 = (const float*)d_in[2];
  const float* Whh0 = (const float*)d_in[3];
  const float* bih0 = (const float*)d_in[4];
  const float* bhh0 = (const float*)d_in[5];
  const float* Wih1 = (const float*)d_in[6];
  const float* Whh1 = (const float*)d_in[7];
  const float* bih1 = (const float*)d_in[8];
  const float* bhh1 = (const float*)d_in[9];
  float* out = (float*)d_out;
  char* ws = (char*)d_ws;

  int* ctrl = (int*)(ws + WS_CTRL);
  int* hist = (int*)(ws + WS_HIST);
  int* offs = (int*)(ws + WS_OFFS);
  unsigned int* sorted = (unsigned int*)(ws + WS_SORT);
  float* bpk = (float*)(ws + WS_BIAS);
  unsigned short* wpkp = (unsigned short*)(ws + WS_WPK);

  hipMemsetAsync(d_ws, 0, 8192, stream);
  k_detect <<<1, 64, 0, stream>>>(ii, ctrl);
  k_extract<<<1, 128, 0, stream>>>(ii, ctrl, hist);
  k_scan   <<<1, 1, 0, stream>>>(ctrl, hist, offs);
  k_scatter<<<1, 128, 0, stream>>>(ii, ctrl, offs, sorted);
  k_packw  <<<Nn*TILES_PER_AGENT, 64, 0, stream>>>(Wih0, Whh0, Wih1, Whh1, wpkp);
  k_packb  <<<32, 256, 0, stream>>>(bih0, bhh0, bih1, bhh1, bpk);
  k_main   <<<256, 512, 0, stream>>>(x, wpkp, bpk, sorted, ctrl, out);
}